// Round 5
// baseline (357.506 us; speedup 1.0000x reference)
//
#include <hip/hip_runtime.h>
#include <math.h>

// Problem constants
#define BB   8
#define SS   100
#define TT   1200        // S * DMAX
#define NM   80          // NMEL
#define DMC  128         // DM
#define KK   9
#define G3   384         // 3*DM
#define NROW (BB*TT)     // 9600

typedef __attribute__((ext_vector_type(8))) short short8;
typedef __attribute__((ext_vector_type(4))) float f32x4;

__device__ __forceinline__ float sigmoid_(float v) { return 1.f / (1.f + __expf(-v)); }
__device__ __forceinline__ float tanh_(float v) {
    float a = fabsf(v);
    float e = __expf(-2.f * a);
    float t = (1.f - e) / (1.f + e);
    return copysignf(t, v);
}
__device__ __forceinline__ unsigned short f2bf(float f) {   // RNE fp32->bf16
    unsigned int u = __float_as_uint(f);
    unsigned int r = (u + 0x7fffu + ((u >> 16) & 1u)) >> 16;
    return (unsigned short)r;
}

// ---------------------------------------------------------------------------
// Kernel S: per-batch prefix sum of durations -> starts[b][s]
// ---------------------------------------------------------------------------
__global__ void k_starts(const int* __restrict__ dur, int* __restrict__ starts) {
    __shared__ int buf[BB][128];
    int s = threadIdx.x;   // 0..127
    int b = threadIdx.y;   // 0..7
    int v = (s < SS) ? dur[b * SS + s] : 0;
    buf[b][s] = v;
    __syncthreads();
    for (int off = 1; off < 128; off <<= 1) {
        int t = (s >= off) ? buf[b][s - off] : 0;
        __syncthreads();
        buf[b][s] += t;
        __syncthreads();
    }
    if (s < SS) starts[b * SS + s] = buf[b][s] - v;  // exclusive scan
}

// ---------------------------------------------------------------------------
// Kernel W (fused): blocks 0..47 pack w_hh; blocks 48..83 pack w_ih + biases.
// A-frag (16x16x32 bf16): lane holds A[m=lane&15][k=(lane>>4)*8 + j], j=0..7
// ---------------------------------------------------------------------------
__global__ void k_wpack_all(const float* __restrict__ whf, const float* __restrict__ whb,
                            const float* __restrict__ wif, const float* __restrict__ wib,
                            const float* __restrict__ bf, const float* __restrict__ bbv,
                            unsigned short* __restrict__ wph, unsigned short* __restrict__ wpl,
                            unsigned short* __restrict__ wih_h, unsigned short* __restrict__ wih_l,
                            float* __restrict__ biasc) {
    int blk = blockIdx.x;
    if (blk < 48) {
        int idx = blk * 256 + threadIdx.x;    // over 2*24*4*64 = 12288
        int lane = idx & 63;
        int k32  = (idx >> 6) & 3;
        int tau  = (idx >> 8) % 24;
        int dir  = idx / (24 * 4 * 64);
        const float* w = dir ? whb : whf;
        int g = tau * 16 + (lane & 15);
        int kbase = k32 * 32 + (lane >> 4) * 8;
#pragma unroll
        for (int j = 0; j < 8; j++) {
            float v = w[g * DMC + kbase + j];
            unsigned short hi = f2bf(v);
            float hif = __uint_as_float(((unsigned)hi) << 16);
            unsigned short lo = f2bf(v - hif);
            wph[idx * 8 + j] = hi;
            wpl[idx * 8 + j] = lo;
        }
    } else {
        int idx = (blk - 48) * 256 + threadIdx.x;   // over 48*3*64 = 9216
        int lane = idx & 63;
        int ks   = (idx >> 6) % 3;
        int tau  = idx / (3 * 64);
        int gate = tau * 16 + (lane & 15);
        int kb   = ks * 32 + (lane >> 4) * 8;
        const float* w = (gate < G3) ? (wif + gate * NM) : (wib + (gate - G3) * NM);
#pragma unroll
        for (int j = 0; j < 8; j++) {
            int k = kb + j;
            float v = (k < NM) ? w[k] : 0.f;
            unsigned short hi = f2bf(v);
            float hif = __uint_as_float(((unsigned)hi) << 16);
            unsigned short lo = f2bf(v - hif);
            wih_h[idx * 8 + j] = hi;
            wih_l[idx * 8 + j] = lo;
        }
        if (idx < 768) biasc[idx] = (idx < G3) ? bf[idx] : bbv[idx - G3];
    }
}

// ---------------------------------------------------------------------------
// Kernel A: fused conv1+BN/ReLU+conv2+BN/ReLU — register-resident.
// Block = 256 thr = 2 rows; thread (r, h, g): d in {g, g+64}, m in [40h,40h+40).
// (256,8): VGPR<=64 -> 8 blocks/CU, LDS ~6.5 KB.
// ---------------------------------------------------------------------------
__global__ __launch_bounds__(256, 8) void k_conv(
    const float* __restrict__ mel, const int* __restrict__ mel_len,
    const float* __restrict__ w1, const float* __restrict__ g1, const float* __restrict__ be1,
    const float* __restrict__ w2, const float* __restrict__ g2, const float* __restrict__ be2,
    float* __restrict__ xout) {
    int b  = blockIdx.y;
    int t0 = blockIdx.x * 2;
    int ml = mel_len[b];
    if (t0 >= ml) return;

    __shared__ __align__(16) float mp[2][96];
    __shared__ __align__(16) float part[2][8][80];   // octet partials

    int tid = threadIdx.x;
    int r = tid >> 7, h = (tid >> 6) & 1, g = tid & 63;
    int ms = 40 * h;
    const float inv_sqrt = 0.9999950000374997f;      // 1/sqrt(1+1e-5)

    if (tid < 192) {
        int rr = tid / 96, i = tid - rr * 96;
        float v = 0.f;
        if (i >= 8 && i < 88) v = mel[(b * TT + t0 + rr) * NM + i - 8];
        mp[rr][i] = v;
    }
    __syncthreads();

    float c[40];
#pragma unroll
    for (int m = 0; m < 40; m++) c[m] = 0.f;

    const float* mprow = mp[r];

#pragma unroll 1
    for (int dd = 0; dd < 2; dd++) {
        int d = g + 64 * dd;
        float sc = g1[d] * inv_sqrt;
        float w1r[KK], w2r[KK];
#pragma unroll
        for (int k = 0; k < KK; k++) { w1r[k] = w1[d * KK + k] * sc; w2r[k] = w2[d * KK + k]; }
        float sb = be1[d];

        float mw[16];
        {
            const float4* p4 = (const float4*)(mprow + ms);
            float4 a = p4[0], bq = p4[1], cq = p4[2], dq = p4[3];
            mw[0]=a.x; mw[1]=a.y; mw[2]=a.z; mw[3]=a.w;
            mw[4]=bq.x; mw[5]=bq.y; mw[6]=bq.z; mw[7]=bq.w;
            mw[8]=cq.x; mw[9]=cq.y; mw[10]=cq.z; mw[11]=cq.w;
            mw[12]=dq.x; mw[13]=dq.y; mw[14]=dq.z; mw[15]=dq.w;
        }
#pragma unroll
        for (int ch = 0; ch < 6; ch++) {
#pragma unroll
            for (int jj = 0; jj < 8; jj++) {
                int off = ch * 8 + jj;
                float yv = sb;
#pragma unroll
                for (int k = 0; k < KK; k++) yv = fmaf(w1r[k], mw[jj + k], yv);
                yv = fmaxf(yv, 0.f);
                int j = ms + off;
                if (j < 4 || j >= 84) yv = 0.f;  // conv1 output halo is zero
#pragma unroll
                for (int k = 0; k < KK; k++) {
                    int mo = off - k;
                    if (mo >= 0 && mo < 40) c[mo] = fmaf(w2r[k], yv, c[mo]);
                }
            }
            if (ch < 5) {
#pragma unroll
                for (int q = 0; q < 8; q++) mw[q] = mw[q + 8];
                const float4* p4 = (const float4*)(mprow + ms + (ch + 1) * 8 + 8);
                float4 a = p4[0], bq = p4[1];
                mw[8]=a.x; mw[9]=a.y; mw[10]=a.z; mw[11]=a.w;
                mw[12]=bq.x; mw[13]=bq.y; mw[14]=bq.z; mw[15]=bq.w;
            }
        }
    }

#pragma unroll
    for (int m = 0; m < 40; m++) {
        c[m] += __shfl_xor(c[m], 1);
        c[m] += __shfl_xor(c[m], 2);
        c[m] += __shfl_xor(c[m], 4);
    }
    if ((g & 7) == 0) {
        int p = g >> 3;
#pragma unroll
        for (int m = 0; m < 40; m += 4)
            *(float4*)&part[r][p][ms + m] = make_float4(c[m], c[m+1], c[m+2], c[m+3]);
    }
    __syncthreads();

    if (tid < 160) {
        int rr = (tid >= 80) ? 1 : 0;
        int m  = tid - 80 * rr;
        int t  = t0 + rr;
        if (t < ml) {
            float s = 0.f;
#pragma unroll
            for (int p = 0; p < 8; p++) s += part[rr][p][m];
            float v = fmaxf(0.f, fmaf(s, g2[0] * inv_sqrt, be2[0]));
            xout[(b * TT + t) * NM + m] = v;
        }
    }
}

// ---------------------------------------------------------------------------
// Kernel B: projection GEMM via split-bf16 MFMA.
// ---------------------------------------------------------------------------
__global__ __launch_bounds__(256) void k_proj(
    const float* __restrict__ x,
    const unsigned short* __restrict__ wih_h, const unsigned short* __restrict__ wih_l,
    const float* __restrict__ biasc,
    float* __restrict__ xall) {
    __shared__ short8 bhs[2 * 3 * 64];
    __shared__ short8 bls[2 * 3 * 64];

    int tid = threadIdx.x;
    int wave = tid >> 6, lane = tid & 63, quad = lane >> 4;
    int row0 = blockIdx.x * 32;
    int tau0 = blockIdx.y * 24;

    for (int i = tid; i < 2 * 3 * 64; i += 256) {
        int rg = i / 192, rem = i - rg * 192;
        int ks = rem >> 6, ln = rem & 63;
        int row = row0 + rg * 16 + (ln & 15);
        int kb = ks * 32 + (ln >> 4) * 8;
        short8 hi8, lo8;
#pragma unroll
        for (int j = 0; j < 8; j++) {
            int k = kb + j;
            float v = (k < NM) ? x[row * NM + k] : 0.f;
            unsigned short hi = f2bf(v);
            float hif = __uint_as_float(((unsigned)hi) << 16);
            hi8[j] = (short)hi;
            lo8[j] = (short)f2bf(v - hif);
        }
        bhs[i] = hi8;
        bls[i] = lo8;
    }
    __syncthreads();

    const short8* wih_h8 = (const short8*)wih_h;
    const short8* wih_l8 = (const short8*)wih_l;

    for (int tt = 0; tt < 6; tt++) {
        int tau = tau0 + wave * 6 + tt;
        short8 Ah[3], Al[3];
#pragma unroll
        for (int ks = 0; ks < 3; ks++) {
            int ia = (tau * 3 + ks) * 64 + lane;
            Ah[ks] = wih_h8[ia];
            Al[ks] = wih_l8[ia];
        }
        f32x4 acc0 = (f32x4){0.f,0.f,0.f,0.f}, acc1 = (f32x4){0.f,0.f,0.f,0.f};
#pragma unroll
        for (int ks = 0; ks < 3; ks++) {
            short8 Bh0 = bhs[ks * 64 + lane],       Bl0 = bls[ks * 64 + lane];
            short8 Bh1 = bhs[192 + ks * 64 + lane], Bl1 = bls[192 + ks * 64 + lane];
            acc0 = __builtin_amdgcn_mfma_f32_16x16x32_bf16(Ah[ks], Bh0, acc0, 0, 0, 0);
            acc0 = __builtin_amdgcn_mfma_f32_16x16x32_bf16(Ah[ks], Bl0, acc0, 0, 0, 0);
            acc0 = __builtin_amdgcn_mfma_f32_16x16x32_bf16(Al[ks], Bh0, acc0, 0, 0, 0);
            acc1 = __builtin_amdgcn_mfma_f32_16x16x32_bf16(Ah[ks], Bh1, acc1, 0, 0, 0);
            acc1 = __builtin_amdgcn_mfma_f32_16x16x32_bf16(Ah[ks], Bl1, acc1, 0, 0, 0);
            acc1 = __builtin_amdgcn_mfma_f32_16x16x32_bf16(Al[ks], Bh1, acc1, 0, 0, 0);
        }
        float4 bias4 = *(const float4*)&biasc[tau * 16 + quad * 4];
        int ga = tau * 16 + quad * 4;
        int rowA = row0 + (lane & 15);
        float4 o0 = make_float4(acc0[0] + bias4.x, acc0[1] + bias4.y,
                                acc0[2] + bias4.z, acc0[3] + bias4.w);
        *(float4*)&xall[rowA * 768 + ga] = o0;
        int rowB = rowA + 16;
        float4 o1 = make_float4(acc1[0] + bias4.x, acc1[1] + bias4.y,
                                acc1[2] + bias4.z, acc1[3] + bias4.w);
        *(float4*)&xall[rowB * 768 + ga] = o1;
    }
}

// ---------------------------------------------------------------------------
// Kernel C: per-segment GRU via MFMA, split-bf16.
// R5: fixed 6-slot unrolled phase-2; x-loads prefetched BEFORE the MFMA phase
// (depend only on sdur/sstart/i) so HBM latency hides behind MFMA+barrier;
// h lives in registers (same thread owns a slot across all iterations).
// ---------------------------------------------------------------------------
__global__ __launch_bounds__(384) void k_gru(
    const float* __restrict__ xall,
    const unsigned short* __restrict__ wph, const unsigned short* __restrict__ wpl,
    const int* __restrict__ dur_all, const int* __restrict__ starts,
    const int* __restrict__ src_len,
    const float* __restrict__ bhf, const float* __restrict__ bhb,
    float* __restrict__ out) {
    int sblk = blockIdx.x;   // 0..6
    int b    = blockIdx.y;   // 0..7
    int dir  = blockIdx.z;   // 0 fwd, 1 bwd
    int s0 = sblk * 16;

    __shared__ __align__(16) unsigned short hbh[4 * 64 * 8];   // B-frag hi
    __shared__ __align__(16) unsigned short hbl[4 * 64 * 8];   // B-frag lo
    __shared__ __align__(16) float gbuf[16][388];              // gates [seg][g]
    __shared__ int sdur[16], sstart[16];

    int tid  = threadIdx.x;
    int wave = tid >> 6, lane = tid & 63;

    if (tid < 16) {
        int s = s0 + tid;
        sdur[tid]   = (s < SS) ? dur_all[b * SS + s] : 0;
        sstart[tid] = (s < SS) ? starts[b * SS + s]  : 0;
    }
    for (int i = tid; i < 2048; i += 384) { hbh[i] = 0; hbl[i] = 0; }

    // ---- load A-fragments once (registers, persist all 12 iterations) ----
    short8 Ah[4][4], Al[4][4];
    const short8* wph8 = (const short8*)wph;
    const short8* wpl8 = (const short8*)wpl;
#pragma unroll
    for (int tt = 0; tt < 4; tt++)
#pragma unroll
        for (int k32 = 0; k32 < 4; k32++) {
            int tau = wave * 4 + tt;
            int idx = ((dir * 24 + tau) * 4 + k32) * 64 + lane;
            Ah[tt][k32] = wph8[idx];
            Al[tt][k32] = wpl8[idx];
        }

    const float* bh = dir ? bhb : bhf;
    int xbase = dir * G3;
    int seg_c = lane & 15, quad = lane >> 4;
    __syncthreads();

    // ---- cache slot metadata in registers (fixed 6 slots per thread) ----
    int sd_[6], st_[6], sseg_[6], sj_[6];
    float h_[6], bhr_[6], bhz_[6], bhn_[6];
#pragma unroll
    for (int q = 0; q < 6; q++) {
        int u = tid + q * 384;
        if (u < 16 * DMC) {
            int seg = u >> 7, j = u & 127;
            sseg_[q] = seg; sj_[q] = j;
            sd_[q] = sdur[seg]; st_[q] = sstart[seg];
            bhr_[q] = bh[j]; bhz_[q] = bh[DMC + j]; bhn_[q] = bh[2 * DMC + j];
        } else {
            sd_[q] = 0; st_[q] = 0; sseg_[q] = 0; sj_[q] = 0;
            bhr_[q] = 0.f; bhz_[q] = 0.f; bhn_[q] = 0.f;
        }
        h_[q] = 0.f;
    }
    int slb = src_len[b];

    for (int i = 0; i < 12; i++) {
        // ---- prefetch this iteration's x-gates (no dependency on LDS state) ----
        float xr_[6], xz_[6], xn_[6];
#pragma unroll
        for (int q = 0; q < 6; q++) {
            if (i < sd_[q]) {
                int t = dir ? (st_[q] + sd_[q] - 1 - i) : (st_[q] + i);
                const float* xrow = xall + (b * TT + t) * 768 + xbase + sj_[q];
                xr_[q] = xrow[0];
                xz_[q] = xrow[DMC];
                xn_[q] = xrow[2 * DMC];
            } else { xr_[q] = 0.f; xz_[q] = 0.f; xn_[q] = 0.f; }
        }

        // ---- phase 1: D[g][seg] = h . w_hh   (3-term split-bf16 MFMA) ----
        f32x4 acc[4];
#pragma unroll
        for (int tt = 0; tt < 4; tt++) acc[tt] = (f32x4){0.f, 0.f, 0.f, 0.f};
#pragma unroll
        for (int k32 = 0; k32 < 4; k32++) {
            short8 Bh = ((const short8*)hbh)[k32 * 64 + lane];
            short8 Bl = ((const short8*)hbl)[k32 * 64 + lane];
#pragma unroll
            for (int tt = 0; tt < 4; tt++) {
                acc[tt] = __builtin_amdgcn_mfma_f32_16x16x32_bf16(Ah[tt][k32], Bh, acc[tt], 0, 0, 0);
                acc[tt] = __builtin_amdgcn_mfma_f32_16x16x32_bf16(Ah[tt][k32], Bl, acc[tt], 0, 0, 0);
                acc[tt] = __builtin_amdgcn_mfma_f32_16x16x32_bf16(Al[tt][k32], Bh, acc[tt], 0, 0, 0);
            }
        }
#pragma unroll
        for (int tt = 0; tt < 4; tt++) {
            int g = (wave * 4 + tt) * 16 + quad * 4;    // row = quad*4+reg (m89)
            *(f32x4*)&gbuf[seg_c][g] = acc[tt];
        }
        __syncthreads();

        // ---- phase 2: elementwise GRU update + output gather ----
#pragma unroll
        for (int q = 0; q < 6; q++) {
            if (i < sd_[q]) {
                int seg = sseg_[q], j = sj_[q];
                float hr = gbuf[seg][j]           + bhr_[q];
                float hz = gbuf[seg][DMC + j]     + bhz_[q];
                float hn = gbuf[seg][2 * DMC + j] + bhn_[q];
                float r = sigmoid_(xr_[q] + hr);
                float z = sigmoid_(xz_[q] + hz);
                float n = tanh_(xn_[q] + r * hn);
                float hnew = (1.f - z) * n + z * h_[q];
                h_[q] = hnew;
                unsigned short hi = f2bf(hnew);
                float hif = __uint_as_float(((unsigned)hi) << 16);
                unsigned short lo = f2bf(hnew - hif);
                int addr = ((j >> 5) * 64 + ((j & 31) >> 3) * 16 + seg) * 8 + (j & 7);
                hbh[addr] = hi;
                hbl[addr] = lo;
                if (i == sd_[q] - 1) {
                    int s = s0 + seg;
                    float vout = (s < slb) ? hnew : 0.f;
                    out[(b * SS + s) * (2 * DMC) + dir * DMC + j] = vout;
                }
            }
        }
        __syncthreads();
    }
}

// ---------------------------------------------------------------------------
extern "C" void kernel_launch(void* const* d_in, const int* in_sizes, int n_in,
                              void* d_out, int out_size, void* d_ws, size_t ws_size,
                              hipStream_t stream) {
    const float* mel      = (const float*)d_in[0];
    const int*   durations= (const int*)  d_in[1];
    const int*   mel_len  = (const int*)  d_in[2];
    const int*   src_len  = (const int*)  d_in[3];
    const float* w1       = (const float*)d_in[4];
    const float* g1       = (const float*)d_in[5];
    const float* be1      = (const float*)d_in[6];
    const float* w2       = (const float*)d_in[7];
    const float* g2       = (const float*)d_in[8];
    const float* be2      = (const float*)d_in[9];
    const float* w_ih_f   = (const float*)d_in[10];
    const float* w_hh_f   = (const float*)d_in[11];
    const float* b_ih_f   = (const float*)d_in[12];
    const float* b_hh_f   = (const float*)d_in[13];
    const float* w_ih_b   = (const float*)d_in[14];
    const float* w_hh_b   = (const float*)d_in[15];
    const float* b_ih_b   = (const float*)d_in[16];
    const float* b_hh_b   = (const float*)d_in[17];
    float* out = (float*)d_out;

    // workspace: x | xall | wph | wpl | wih_h | wih_l | biasc | starts
    float* x    = (float*)d_ws;
    float* xall = x + NROW * NM;
    unsigned short* wph   = (unsigned short*)(xall + NROW * 768);
    unsigned short* wpl   = wph + 2 * 24 * 4 * 64 * 8;
    unsigned short* wih_h = wpl + 2 * 24 * 4 * 64 * 8;
    unsigned short* wih_l = wih_h + 48 * 3 * 64 * 8;
    float* biasc = (float*)(wih_l + 48 * 3 * 64 * 8);
    int*   starts= (int*)(biasc + 768);

    k_starts<<<1, dim3(128, 8), 0, stream>>>(durations, starts);
    k_wpack_all<<<84, 256, 0, stream>>>(w_hh_f, w_hh_b, w_ih_f, w_ih_b, b_ih_f, b_ih_b,
                                        wph, wpl, wih_h, wih_l, biasc);
    k_conv<<<dim3(TT / 2, BB), 256, 0, stream>>>(mel, mel_len, w1, g1, be1, w2, g2, be2, x);
    k_proj<<<dim3(NROW / 32, 2), 256, 0, stream>>>(x, wih_h, wih_l, biasc, xall);
    k_gru<<<dim3(7, 8, 2), 384, 0, stream>>>(xall, wph, wpl, durations, starts, src_len,
                                             b_hh_f, b_hh_b, out);
}

// Round 6
// 193.679 us; speedup vs baseline: 1.8459x; 1.8459x over previous
//
#include <hip/hip_runtime.h>
#include <math.h>

// Problem constants
#define BB   8
#define SS   100
#define TT   1200        // S * DMAX
#define NM   80          // NMEL
#define DMC  128         // DM
#define KK   9
#define G3   384         // 3*DM
#define NROW (BB*TT)     // 9600

typedef __attribute__((ext_vector_type(8))) short short8;
typedef __attribute__((ext_vector_type(4))) float f32x4;

__device__ __forceinline__ float sigmoid_(float v) { return 1.f / (1.f + __expf(-v)); }
__device__ __forceinline__ float tanh_(float v) {
    float a = fabsf(v);
    float e = __expf(-2.f * a);
    float t = (1.f - e) / (1.f + e);
    return copysignf(t, v);
}
__device__ __forceinline__ unsigned short f2bf(float f) {   // RNE fp32->bf16
    unsigned int u = __float_as_uint(f);
    unsigned int r = (u + 0x7fffu + ((u >> 16) & 1u)) >> 16;
    return (unsigned short)r;
}

// ---------------------------------------------------------------------------
// Kernel P (fused prep), 22 blocks x 1024 thr:
//   blk 0..11  : pack w_hh into A-frag split-bf16 (12288 frags-lanes)
//   blk 12..20 : pack w_ih into A-frag split-bf16 (9216)
//   blk 21     : durations prefix-scan -> starts; concat biases
// A-frag (16x16x32 bf16): lane holds A[m=lane&15][k=(lane>>4)*8 + j], j=0..7
// ---------------------------------------------------------------------------
__global__ __launch_bounds__(1024) void k_prep(
    const float* __restrict__ whf, const float* __restrict__ whb,
    const float* __restrict__ wif, const float* __restrict__ wib,
    const float* __restrict__ bf, const float* __restrict__ bbv,
    const int* __restrict__ dur,
    unsigned short* __restrict__ wph, unsigned short* __restrict__ wpl,
    unsigned short* __restrict__ wih_h, unsigned short* __restrict__ wih_l,
    float* __restrict__ biasc, int* __restrict__ starts) {
    int blk = blockIdx.x;
    int tid = threadIdx.x;
    if (blk < 12) {
        int idx = blk * 1024 + tid;           // [0, 12288)
        int lane = idx & 63;
        int k32  = (idx >> 6) & 3;
        int tau  = (idx >> 8) % 24;
        int dir  = idx / (24 * 4 * 64);
        const float* w = dir ? whb : whf;
        int g = tau * 16 + (lane & 15);
        int kbase = k32 * 32 + (lane >> 4) * 8;
#pragma unroll
        for (int j = 0; j < 8; j++) {
            float v = w[g * DMC + kbase + j];
            unsigned short hi = f2bf(v);
            float hif = __uint_as_float(((unsigned)hi) << 16);
            unsigned short lo = f2bf(v - hif);
            wph[idx * 8 + j] = hi;
            wpl[idx * 8 + j] = lo;
        }
    } else if (blk < 21) {
        int idx = (blk - 12) * 1024 + tid;    // [0, 9216)
        int lane = idx & 63;
        int ks   = (idx >> 6) % 3;
        int tau  = idx / (3 * 64);
        int gate = tau * 16 + (lane & 15);
        int kb   = ks * 32 + (lane >> 4) * 8;
        const float* w = (gate < G3) ? (wif + gate * NM) : (wib + (gate - G3) * NM);
#pragma unroll
        for (int j = 0; j < 8; j++) {
            int k = kb + j;
            float v = (k < NM) ? w[k] : 0.f;
            unsigned short hi = f2bf(v);
            float hif = __uint_as_float(((unsigned)hi) << 16);
            unsigned short lo = f2bf(v - hif);
            wih_h[idx * 8 + j] = hi;
            wih_l[idx * 8 + j] = lo;
        }
    } else {
        // prefix scan of durations + bias concat
        __shared__ int buf[BB][128];
        int s = tid & 127, b = tid >> 7;
        int v = (s < SS) ? dur[b * SS + s] : 0;
        buf[b][s] = v;
        __syncthreads();
        for (int off = 1; off < 128; off <<= 1) {
            int t = (s >= off) ? buf[b][s - off] : 0;
            __syncthreads();
            buf[b][s] += t;
            __syncthreads();
        }
        if (s < SS) starts[b * SS + s] = buf[b][s] - v;
        if (tid < 768) biasc[tid] = (tid < G3) ? bf[tid] : bbv[tid - G3];
    }
}

// ---------------------------------------------------------------------------
// Kernel A: fused conv1+BN/ReLU+conv2+BN/ReLU — register-resident.
// Block = 256 thr = 2 rows; thread (r, h, g): d in {g, g+64}, m in [40h,40h+40).
// waves_per_eu(4,4): VGPR budget 128 (working set ~90) -> NO SPILLS; the
// (256,8)/default-8-waves heuristic clamps VGPR to 64/32 and spills (R4/R5).
// ---------------------------------------------------------------------------
__global__ __attribute__((amdgpu_flat_work_group_size(256, 256), amdgpu_waves_per_eu(4, 4)))
void k_conv(
    const float* __restrict__ mel, const int* __restrict__ mel_len,
    const float* __restrict__ w1, const float* __restrict__ g1, const float* __restrict__ be1,
    const float* __restrict__ w2, const float* __restrict__ g2, const float* __restrict__ be2,
    float* __restrict__ xout) {
    int b  = blockIdx.y;
    int t0 = blockIdx.x * 2;
    int ml = mel_len[b];
    if (t0 >= ml) return;

    __shared__ __align__(16) float mp[2][96];
    __shared__ __align__(16) float part[2][8][80];   // octet partials

    int tid = threadIdx.x;
    int r = tid >> 7, h = (tid >> 6) & 1, g = tid & 63;
    int ms = 40 * h;
    const float inv_sqrt = 0.9999950000374997f;      // 1/sqrt(1+1e-5)

    if (tid < 192) {
        int rr = tid / 96, i = tid - rr * 96;
        float v = 0.f;
        if (i >= 8 && i < 88) v = mel[(b * TT + t0 + rr) * NM + i - 8];
        mp[rr][i] = v;
    }
    __syncthreads();

    float c[40];
#pragma unroll
    for (int m = 0; m < 40; m++) c[m] = 0.f;

    const float* mprow = mp[r];

#pragma unroll 1
    for (int dd = 0; dd < 2; dd++) {
        int d = g + 64 * dd;
        float sc = g1[d] * inv_sqrt;
        float w1r[KK], w2r[KK];
#pragma unroll
        for (int k = 0; k < KK; k++) { w1r[k] = w1[d * KK + k] * sc; w2r[k] = w2[d * KK + k]; }
        float sb = be1[d];

        float mw[16];
        {
            const float4* p4 = (const float4*)(mprow + ms);
            float4 a = p4[0], bq = p4[1], cq = p4[2], dq = p4[3];
            mw[0]=a.x; mw[1]=a.y; mw[2]=a.z; mw[3]=a.w;
            mw[4]=bq.x; mw[5]=bq.y; mw[6]=bq.z; mw[7]=bq.w;
            mw[8]=cq.x; mw[9]=cq.y; mw[10]=cq.z; mw[11]=cq.w;
            mw[12]=dq.x; mw[13]=dq.y; mw[14]=dq.z; mw[15]=dq.w;
        }
#pragma unroll
        for (int ch = 0; ch < 6; ch++) {
#pragma unroll
            for (int jj = 0; jj < 8; jj++) {
                int off = ch * 8 + jj;
                float yv = sb;
#pragma unroll
                for (int k = 0; k < KK; k++) yv = fmaf(w1r[k], mw[jj + k], yv);
                yv = fmaxf(yv, 0.f);
                int j = ms + off;
                if (j < 4 || j >= 84) yv = 0.f;  // conv1 output halo is zero
#pragma unroll
                for (int k = 0; k < KK; k++) {
                    int mo = off - k;
                    if (mo >= 0 && mo < 40) c[mo] = fmaf(w2r[k], yv, c[mo]);
                }
            }
            if (ch < 5) {
#pragma unroll
                for (int q = 0; q < 8; q++) mw[q] = mw[q + 8];
                const float4* p4 = (const float4*)(mprow + ms + (ch + 1) * 8 + 8);
                float4 a = p4[0], bq = p4[1];
                mw[8]=a.x; mw[9]=a.y; mw[10]=a.z; mw[11]=a.w;
                mw[12]=bq.x; mw[13]=bq.y; mw[14]=bq.z; mw[15]=bq.w;
            }
        }
    }

#pragma unroll
    for (int m = 0; m < 40; m++) {
        c[m] += __shfl_xor(c[m], 1);
        c[m] += __shfl_xor(c[m], 2);
        c[m] += __shfl_xor(c[m], 4);
    }
    if ((g & 7) == 0) {
        int p = g >> 3;
#pragma unroll
        for (int m = 0; m < 40; m += 4)
            *(float4*)&part[r][p][ms + m] = make_float4(c[m], c[m+1], c[m+2], c[m+3]);
    }
    __syncthreads();

    if (tid < 160) {
        int rr = (tid >= 80) ? 1 : 0;
        int m  = tid - 80 * rr;
        int t  = t0 + rr;
        if (t < ml) {
            float s = 0.f;
#pragma unroll
            for (int p = 0; p < 8; p++) s += part[rr][p][m];
            float v = fmaxf(0.f, fmaf(s, g2[0] * inv_sqrt, be2[0]));
            xout[(b * TT + t) * NM + m] = v;
        }
    }
}

// ---------------------------------------------------------------------------
// Kernel B: projection GEMM via split-bf16 MFMA.
// ---------------------------------------------------------------------------
__global__ __launch_bounds__(256) void k_proj(
    const float* __restrict__ x,
    const unsigned short* __restrict__ wih_h, const unsigned short* __restrict__ wih_l,
    const float* __restrict__ biasc,
    float* __restrict__ xall) {
    __shared__ short8 bhs[2 * 3 * 64];
    __shared__ short8 bls[2 * 3 * 64];

    int tid = threadIdx.x;
    int wave = tid >> 6, lane = tid & 63, quad = lane >> 4;
    int row0 = blockIdx.x * 32;
    int tau0 = blockIdx.y * 24;

    for (int i = tid; i < 2 * 3 * 64; i += 256) {
        int rg = i / 192, rem = i - rg * 192;
        int ks = rem >> 6, ln = rem & 63;
        int row = row0 + rg * 16 + (ln & 15);
        int kb = ks * 32 + (ln >> 4) * 8;
        short8 hi8, lo8;
#pragma unroll
        for (int j = 0; j < 8; j++) {
            int k = kb + j;
            float v = (k < NM) ? x[row * NM + k] : 0.f;
            unsigned short hi = f2bf(v);
            float hif = __uint_as_float(((unsigned)hi) << 16);
            hi8[j] = (short)hi;
            lo8[j] = (short)f2bf(v - hif);
        }
        bhs[i] = hi8;
        bls[i] = lo8;
    }
    __syncthreads();

    const short8* wih_h8 = (const short8*)wih_h;
    const short8* wih_l8 = (const short8*)wih_l;

    for (int tt = 0; tt < 6; tt++) {
        int tau = tau0 + wave * 6 + tt;
        short8 Ah[3], Al[3];
#pragma unroll
        for (int ks = 0; ks < 3; ks++) {
            int ia = (tau * 3 + ks) * 64 + lane;
            Ah[ks] = wih_h8[ia];
            Al[ks] = wih_l8[ia];
        }
        f32x4 acc0 = (f32x4){0.f,0.f,0.f,0.f}, acc1 = (f32x4){0.f,0.f,0.f,0.f};
#pragma unroll
        for (int ks = 0; ks < 3; ks++) {
            short8 Bh0 = bhs[ks * 64 + lane],       Bl0 = bls[ks * 64 + lane];
            short8 Bh1 = bhs[192 + ks * 64 + lane], Bl1 = bls[192 + ks * 64 + lane];
            acc0 = __builtin_amdgcn_mfma_f32_16x16x32_bf16(Ah[ks], Bh0, acc0, 0, 0, 0);
            acc0 = __builtin_amdgcn_mfma_f32_16x16x32_bf16(Ah[ks], Bl0, acc0, 0, 0, 0);
            acc0 = __builtin_amdgcn_mfma_f32_16x16x32_bf16(Al[ks], Bh0, acc0, 0, 0, 0);
            acc1 = __builtin_amdgcn_mfma_f32_16x16x32_bf16(Ah[ks], Bh1, acc1, 0, 0, 0);
            acc1 = __builtin_amdgcn_mfma_f32_16x16x32_bf16(Ah[ks], Bl1, acc1, 0, 0, 0);
            acc1 = __builtin_amdgcn_mfma_f32_16x16x32_bf16(Al[ks], Bh1, acc1, 0, 0, 0);
        }
        float4 bias4 = *(const float4*)&biasc[tau * 16 + quad * 4];
        int ga = tau * 16 + quad * 4;
        int rowA = row0 + (lane & 15);
        float4 o0 = make_float4(acc0[0] + bias4.x, acc0[1] + bias4.y,
                                acc0[2] + bias4.z, acc0[3] + bias4.w);
        *(float4*)&xall[rowA * 768 + ga] = o0;
        int rowB = rowA + 16;
        float4 o1 = make_float4(acc1[0] + bias4.x, acc1[1] + bias4.y,
                                acc1[2] + bias4.z, acc1[3] + bias4.w);
        *(float4*)&xall[rowB * 768 + ga] = o1;
    }
}

// ---------------------------------------------------------------------------
// Kernel C: per-segment GRU via MFMA, split-bf16 (R5 structure kept).
// ---------------------------------------------------------------------------
__global__ __launch_bounds__(384) void k_gru(
    const float* __restrict__ xall,
    const unsigned short* __restrict__ wph, const unsigned short* __restrict__ wpl,
    const int* __restrict__ dur_all, const int* __restrict__ starts,
    const int* __restrict__ src_len,
    const float* __restrict__ bhf, const float* __restrict__ bhb,
    float* __restrict__ out) {
    int sblk = blockIdx.x;   // 0..6
    int b    = blockIdx.y;   // 0..7
    int dir  = blockIdx.z;   // 0 fwd, 1 bwd
    int s0 = sblk * 16;

    __shared__ __align__(16) unsigned short hbh[4 * 64 * 8];   // B-frag hi
    __shared__ __align__(16) unsigned short hbl[4 * 64 * 8];   // B-frag lo
    __shared__ __align__(16) float gbuf[16][388];              // gates [seg][g]
    __shared__ int sdur[16], sstart[16];

    int tid  = threadIdx.x;
    int wave = tid >> 6, lane = tid & 63;

    if (tid < 16) {
        int s = s0 + tid;
        sdur[tid]   = (s < SS) ? dur_all[b * SS + s] : 0;
        sstart[tid] = (s < SS) ? starts[b * SS + s]  : 0;
    }
    for (int i = tid; i < 2048; i += 384) { hbh[i] = 0; hbl[i] = 0; }

    short8 Ah[4][4], Al[4][4];
    const short8* wph8 = (const short8*)wph;
    const short8* wpl8 = (const short8*)wpl;
#pragma unroll
    for (int tt = 0; tt < 4; tt++)
#pragma unroll
        for (int k32 = 0; k32 < 4; k32++) {
            int tau = wave * 4 + tt;
            int idx = ((dir * 24 + tau) * 4 + k32) * 64 + lane;
            Ah[tt][k32] = wph8[idx];
            Al[tt][k32] = wpl8[idx];
        }

    const float* bh = dir ? bhb : bhf;
    int xbase = dir * G3;
    int seg_c = lane & 15, quad = lane >> 4;
    __syncthreads();

    int sd_[6], st_[6], sseg_[6], sj_[6];
    float h_[6], bhr_[6], bhz_[6], bhn_[6];
#pragma unroll
    for (int q = 0; q < 6; q++) {
        int u = tid + q * 384;
        if (u < 16 * DMC) {
            int seg = u >> 7, j = u & 127;
            sseg_[q] = seg; sj_[q] = j;
            sd_[q] = sdur[seg]; st_[q] = sstart[seg];
            bhr_[q] = bh[j]; bhz_[q] = bh[DMC + j]; bhn_[q] = bh[2 * DMC + j];
        } else {
            sd_[q] = 0; st_[q] = 0; sseg_[q] = 0; sj_[q] = 0;
            bhr_[q] = 0.f; bhz_[q] = 0.f; bhn_[q] = 0.f;
        }
        h_[q] = 0.f;
    }
    int slb = src_len[b];

    for (int i = 0; i < 12; i++) {
        float xr_[6], xz_[6], xn_[6];
#pragma unroll
        for (int q = 0; q < 6; q++) {
            if (i < sd_[q]) {
                int t = dir ? (st_[q] + sd_[q] - 1 - i) : (st_[q] + i);
                const float* xrow = xall + (b * TT + t) * 768 + xbase + sj_[q];
                xr_[q] = xrow[0];
                xz_[q] = xrow[DMC];
                xn_[q] = xrow[2 * DMC];
            } else { xr_[q] = 0.f; xz_[q] = 0.f; xn_[q] = 0.f; }
        }

        f32x4 acc[4];
#pragma unroll
        for (int tt = 0; tt < 4; tt++) acc[tt] = (f32x4){0.f, 0.f, 0.f, 0.f};
#pragma unroll
        for (int k32 = 0; k32 < 4; k32++) {
            short8 Bh = ((const short8*)hbh)[k32 * 64 + lane];
            short8 Bl = ((const short8*)hbl)[k32 * 64 + lane];
#pragma unroll
            for (int tt = 0; tt < 4; tt++) {
                acc[tt] = __builtin_amdgcn_mfma_f32_16x16x32_bf16(Ah[tt][k32], Bh, acc[tt], 0, 0, 0);
                acc[tt] = __builtin_amdgcn_mfma_f32_16x16x32_bf16(Ah[tt][k32], Bl, acc[tt], 0, 0, 0);
                acc[tt] = __builtin_amdgcn_mfma_f32_16x16x32_bf16(Al[tt][k32], Bh, acc[tt], 0, 0, 0);
            }
        }
#pragma unroll
        for (int tt = 0; tt < 4; tt++) {
            int g = (wave * 4 + tt) * 16 + quad * 4;    // row = quad*4+reg (m89)
            *(f32x4*)&gbuf[seg_c][g] = acc[tt];
        }
        __syncthreads();

#pragma unroll
        for (int q = 0; q < 6; q++) {
            if (i < sd_[q]) {
                int seg = sseg_[q], j = sj_[q];
                float hr = gbuf[seg][j]           + bhr_[q];
                float hz = gbuf[seg][DMC + j]     + bhz_[q];
                float hn = gbuf[seg][2 * DMC + j] + bhn_[q];
                float r = sigmoid_(xr_[q] + hr);
                float z = sigmoid_(xz_[q] + hz);
                float n = tanh_(xn_[q] + r * hn);
                float hnew = (1.f - z) * n + z * h_[q];
                h_[q] = hnew;
                unsigned short hi = f2bf(hnew);
                float hif = __uint_as_float(((unsigned)hi) << 16);
                unsigned short lo = f2bf(hnew - hif);
                int addr = ((j >> 5) * 64 + ((j & 31) >> 3) * 16 + seg) * 8 + (j & 7);
                hbh[addr] = hi;
                hbl[addr] = lo;
                if (i == sd_[q] - 1) {
                    int s = s0 + seg;
                    float vout = (s < slb) ? hnew : 0.f;
                    out[(b * SS + s) * (2 * DMC) + dir * DMC + j] = vout;
                }
            }
        }
        __syncthreads();
    }
}

// ---------------------------------------------------------------------------
extern "C" void kernel_launch(void* const* d_in, const int* in_sizes, int n_in,
                              void* d_out, int out_size, void* d_ws, size_t ws_size,
                              hipStream_t stream) {
    const float* mel      = (const float*)d_in[0];
    const int*   durations= (const int*)  d_in[1];
    const int*   mel_len  = (const int*)  d_in[2];
    const int*   src_len  = (const int*)  d_in[3];
    const float* w1       = (const float*)d_in[4];
    const float* g1       = (const float*)d_in[5];
    const float* be1      = (const float*)d_in[6];
    const float* w2       = (const float*)d_in[7];
    const float* g2       = (const float*)d_in[8];
    const float* be2      = (const float*)d_in[9];
    const float* w_ih_f   = (const float*)d_in[10];
    const float* w_hh_f   = (const float*)d_in[11];
    const float* b_ih_f   = (const float*)d_in[12];
    const float* b_hh_f   = (const float*)d_in[13];
    const float* w_ih_b   = (const float*)d_in[14];
    const float* w_hh_b   = (const float*)d_in[15];
    const float* b_ih_b   = (const float*)d_in[16];
    const float* b_hh_b   = (const float*)d_in[17];
    float* out = (float*)d_out;

    // workspace: x | xall | wph | wpl | wih_h | wih_l | biasc | starts
    float* x    = (float*)d_ws;
    float* xall = x + NROW * NM;
    unsigned short* wph   = (unsigned short*)(xall + NROW * 768);
    unsigned short* wpl   = wph + 2 * 24 * 4 * 64 * 8;
    unsigned short* wih_h = wpl + 2 * 24 * 4 * 64 * 8;
    unsigned short* wih_l = wih_h + 48 * 3 * 64 * 8;
    float* biasc = (float*)(wih_l + 48 * 3 * 64 * 8);
    int*   starts= (int*)(biasc + 768);

    k_prep<<<22, 1024, 0, stream>>>(w_hh_f, w_hh_b, w_ih_f, w_ih_b, b_ih_f, b_ih_b,
                                    durations, wph, wpl, wih_h, wih_l, biasc, starts);
    k_conv<<<dim3(TT / 2, BB), 256, 0, stream>>>(mel, mel_len, w1, g1, be1, w2, g2, be2, x);
    k_proj<<<dim3(NROW / 32, 2), 256, 0, stream>>>(x, wih_h, wih_l, biasc, xall);
    k_gru<<<dim3(7, 8, 2), 384, 0, stream>>>(xall, wph, wpl, durations, starts, src_len,
                                             b_hh_f, b_hh_b, out);
}

// Round 7
// 188.842 us; speedup vs baseline: 1.8931x; 1.0256x over previous
//
#include <hip/hip_runtime.h>
#include <math.h>

// Problem constants
#define BB   8
#define SS   100
#define TT   1200        // S * DMAX
#define NM   80          // NMEL
#define DMC  128         // DM
#define KK   9
#define G3   384         // 3*DM
#define NROW (BB*TT)     // 9600

typedef __attribute__((ext_vector_type(8))) short short8;
typedef __attribute__((ext_vector_type(4))) float f32x4;

__device__ __forceinline__ float sigmoid_(float v) { return 1.f / (1.f + __expf(-v)); }
__device__ __forceinline__ float tanh_(float v) {
    float a = fabsf(v);
    float e = __expf(-2.f * a);
    float t = (1.f - e) / (1.f + e);
    return copysignf(t, v);
}
__device__ __forceinline__ unsigned short f2bf(float f) {   // RNE fp32->bf16
    unsigned int u = __float_as_uint(f);
    unsigned int r = (u + 0x7fffu + ((u >> 16) & 1u)) >> 16;
    return (unsigned short)r;
}

// ---------------------------------------------------------------------------
// Kernel P (fused prep), 22 blocks x 1024 thr:
//   blk 0..11  : pack w_hh into A-frag split-bf16
//   blk 12..20 : pack w_ih into A-frag split-bf16
//   blk 21     : durations prefix-scan -> starts; concat biases
// ---------------------------------------------------------------------------
__global__ __launch_bounds__(1024) void k_prep(
    const float* __restrict__ whf, const float* __restrict__ whb,
    const float* __restrict__ wif, const float* __restrict__ wib,
    const float* __restrict__ bf, const float* __restrict__ bbv,
    const int* __restrict__ dur,
    unsigned short* __restrict__ wph, unsigned short* __restrict__ wpl,
    unsigned short* __restrict__ wih_h, unsigned short* __restrict__ wih_l,
    float* __restrict__ biasc, int* __restrict__ starts) {
    int blk = blockIdx.x;
    int tid = threadIdx.x;
    if (blk < 12) {
        int idx = blk * 1024 + tid;           // [0, 12288)
        int lane = idx & 63;
        int k32  = (idx >> 6) & 3;
        int tau  = (idx >> 8) % 24;
        int dir  = idx / (24 * 4 * 64);
        const float* w = dir ? whb : whf;
        int g = tau * 16 + (lane & 15);
        int kbase = k32 * 32 + (lane >> 4) * 8;
#pragma unroll
        for (int j = 0; j < 8; j++) {
            float v = w[g * DMC + kbase + j];
            unsigned short hi = f2bf(v);
            float hif = __uint_as_float(((unsigned)hi) << 16);
            unsigned short lo = f2bf(v - hif);
            wph[idx * 8 + j] = hi;
            wpl[idx * 8 + j] = lo;
        }
    } else if (blk < 21) {
        int idx = (blk - 12) * 1024 + tid;    // [0, 9216)
        int lane = idx & 63;
        int ks   = (idx >> 6) % 3;
        int tau  = idx / (3 * 64);
        int gate = tau * 16 + (lane & 15);
        int kb   = ks * 32 + (lane >> 4) * 8;
        const float* w = (gate < G3) ? (wif + gate * NM) : (wib + (gate - G3) * NM);
#pragma unroll
        for (int j = 0; j < 8; j++) {
            int k = kb + j;
            float v = (k < NM) ? w[k] : 0.f;
            unsigned short hi = f2bf(v);
            float hif = __uint_as_float(((unsigned)hi) << 16);
            unsigned short lo = f2bf(v - hif);
            wih_h[idx * 8 + j] = hi;
            wih_l[idx * 8 + j] = lo;
        }
    } else {
        __shared__ int buf[BB][128];
        int s = tid & 127, b = tid >> 7;
        int v = (s < SS) ? dur[b * SS + s] : 0;
        buf[b][s] = v;
        __syncthreads();
        for (int off = 1; off < 128; off <<= 1) {
            int t = (s >= off) ? buf[b][s - off] : 0;
            __syncthreads();
            buf[b][s] += t;
            __syncthreads();
        }
        if (s < SS) starts[b * SS + s] = buf[b][s] - v;
        if (tid < 768) biasc[tid] = (tid < G3) ? bf[tid] : bbv[tid - G3];
    }
}

// ---------------------------------------------------------------------------
// Kernel A: fused conv1+BN/ReLU+conv2+BN/ReLU — register-resident, SPILL-FREE.
// 1 row/block (9600 blocks), 256 thr = 4 m-quarters x 64 g.
// Thread: d in {g, g+64} (unroll-1 loop, regs reused), 20 outputs (c[20]),
// 12-float sliding mel window. Working set ~60 VGPR -> fits default 64 budget
// (R4/R6 c[40]+mw[16] variant needed ~90 and spilled 35 MB of scratch).
// ---------------------------------------------------------------------------
__global__ __launch_bounds__(256) void k_conv(
    const float* __restrict__ mel, const int* __restrict__ mel_len,
    const float* __restrict__ w1, const float* __restrict__ g1, const float* __restrict__ be1,
    const float* __restrict__ w2, const float* __restrict__ g2, const float* __restrict__ be2,
    float* __restrict__ xout) {
    int b = blockIdx.y;
    int t = blockIdx.x;
    int ml = mel_len[b];
    if (t >= ml) return;

    __shared__ __align__(16) float mp[96];          // mp[i] = mel[i-8], i in [8,88)
    __shared__ __align__(16) float part[8][84];     // octet partials (pad 84: 20 mod 32)

    int tid = threadIdx.x;
    int mq = tid >> 6, g = tid & 63;                // wave = mq, lane = g
    int ms = 20 * mq;
    const float inv_sqrt = 0.9999950000374997f;     // 1/sqrt(1+1e-5)

    if (tid < 96) {
        float v = 0.f;
        if (tid >= 8 && tid < 88) v = mel[(b * TT + t) * NM + tid - 8];
        mp[tid] = v;
    }
    __syncthreads();

    float c[20];
#pragma unroll
    for (int m = 0; m < 20; m++) c[m] = 0.f;

#pragma unroll 1
    for (int dd = 0; dd < 2; dd++) {
        int d = g + 64 * dd;
        float sc = g1[d] * inv_sqrt;
        float w1r[KK], w2r[KK];
#pragma unroll
        for (int k = 0; k < KK; k++) { w1r[k] = w1[d * KK + k] * sc; w2r[k] = w2[d * KK + k]; }
        float sb = be1[d];

        float mw[12];   // sliding window mp[ms+4*ch .. +12)
        {
            const float4* p4 = (const float4*)(mp + ms);
            float4 a = p4[0], bq = p4[1], cq = p4[2];
            mw[0]=a.x;  mw[1]=a.y;  mw[2]=a.z;  mw[3]=a.w;
            mw[4]=bq.x; mw[5]=bq.y; mw[6]=bq.z; mw[7]=bq.w;
            mw[8]=cq.x; mw[9]=cq.y; mw[10]=cq.z; mw[11]=cq.w;
        }
#pragma unroll
        for (int ch = 0; ch < 7; ch++) {            // 7 chunks of 4 y1 = 28 y1
#pragma unroll
            for (int jj = 0; jj < 4; jj++) {
                int off = ch * 4 + jj;              // y1 index j = ms + off
                float yv = sb;
#pragma unroll
                for (int k = 0; k < KK; k++) yv = fmaf(w1r[k], mw[jj + k], yv);
                yv = fmaxf(yv, 0.f);
                int j = ms + off;
                if (j < 4 || j >= 84) yv = 0.f;     // conv1 halo is zero (static)
#pragma unroll
                for (int k = 0; k < KK; k++) {      // scatter into c[off-k]
                    int mo = off - k;
                    if (mo >= 0 && mo < 20) c[mo] = fmaf(w2r[k], yv, c[mo]);
                }
            }
            if (ch < 6) {                           // slide window by 4
#pragma unroll
                for (int q = 0; q < 8; q++) mw[q] = mw[q + 4];
                const float4* p4 = (const float4*)(mp + ms + ch * 4 + 12);
                float4 a = p4[0];
                mw[8]=a.x; mw[9]=a.y; mw[10]=a.z; mw[11]=a.w;
            }
        }
    }

    // ---- butterfly reduce over g within octets ----
#pragma unroll
    for (int m = 0; m < 20; m++) {
        c[m] += __shfl_xor(c[m], 1);
        c[m] += __shfl_xor(c[m], 2);
        c[m] += __shfl_xor(c[m], 4);
    }
    if ((g & 7) == 0) {
        int p = g >> 3;
#pragma unroll
        for (int m = 0; m < 20; m += 4)
            *(float4*)&part[p][ms + m] = make_float4(c[m], c[m+1], c[m+2], c[m+3]);
    }
    __syncthreads();

    // ---- final: sum 8 octet partials + BN2/ReLU + store ----
    if (tid < 80) {
        float s = 0.f;
#pragma unroll
        for (int p = 0; p < 8; p++) s += part[p][tid];
        float v = fmaxf(0.f, fmaf(s, g2[0] * inv_sqrt, be2[0]));
        xout[(b * TT + t) * NM + tid] = v;
    }
}

// ---------------------------------------------------------------------------
// Kernel B: projection GEMM via split-bf16 MFMA.
// ---------------------------------------------------------------------------
__global__ __launch_bounds__(256) void k_proj(
    const float* __restrict__ x,
    const unsigned short* __restrict__ wih_h, const unsigned short* __restrict__ wih_l,
    const float* __restrict__ biasc,
    float* __restrict__ xall) {
    __shared__ short8 bhs[2 * 3 * 64];
    __shared__ short8 bls[2 * 3 * 64];

    int tid = threadIdx.x;
    int wave = tid >> 6, lane = tid & 63, quad = lane >> 4;
    int row0 = blockIdx.x * 32;
    int tau0 = blockIdx.y * 24;

    for (int i = tid; i < 2 * 3 * 64; i += 256) {
        int rg = i / 192, rem = i - rg * 192;
        int ks = rem >> 6, ln = rem & 63;
        int row = row0 + rg * 16 + (ln & 15);
        int kb = ks * 32 + (ln >> 4) * 8;
        short8 hi8, lo8;
#pragma unroll
        for (int j = 0; j < 8; j++) {
            int k = kb + j;
            float v = (k < NM) ? x[row * NM + k] : 0.f;
            unsigned short hi = f2bf(v);
            float hif = __uint_as_float(((unsigned)hi) << 16);
            hi8[j] = (short)hi;
            lo8[j] = (short)f2bf(v - hif);
        }
        bhs[i] = hi8;
        bls[i] = lo8;
    }
    __syncthreads();

    const short8* wih_h8 = (const short8*)wih_h;
    const short8* wih_l8 = (const short8*)wih_l;

    for (int tt = 0; tt < 6; tt++) {
        int tau = tau0 + wave * 6 + tt;
        short8 Ah[3], Al[3];
#pragma unroll
        for (int ks = 0; ks < 3; ks++) {
            int ia = (tau * 3 + ks) * 64 + lane;
            Ah[ks] = wih_h8[ia];
            Al[ks] = wih_l8[ia];
        }
        f32x4 acc0 = (f32x4){0.f,0.f,0.f,0.f}, acc1 = (f32x4){0.f,0.f,0.f,0.f};
#pragma unroll
        for (int ks = 0; ks < 3; ks++) {
            short8 Bh0 = bhs[ks * 64 + lane],       Bl0 = bls[ks * 64 + lane];
            short8 Bh1 = bhs[192 + ks * 64 + lane], Bl1 = bls[192 + ks * 64 + lane];
            acc0 = __builtin_amdgcn_mfma_f32_16x16x32_bf16(Ah[ks], Bh0, acc0, 0, 0, 0);
            acc0 = __builtin_amdgcn_mfma_f32_16x16x32_bf16(Ah[ks], Bl0, acc0, 0, 0, 0);
            acc0 = __builtin_amdgcn_mfma_f32_16x16x32_bf16(Al[ks], Bh0, acc0, 0, 0, 0);
            acc1 = __builtin_amdgcn_mfma_f32_16x16x32_bf16(Ah[ks], Bh1, acc1, 0, 0, 0);
            acc1 = __builtin_amdgcn_mfma_f32_16x16x32_bf16(Ah[ks], Bl1, acc1, 0, 0, 0);
            acc1 = __builtin_amdgcn_mfma_f32_16x16x32_bf16(Al[ks], Bh1, acc1, 0, 0, 0);
        }
        float4 bias4 = *(const float4*)&biasc[tau * 16 + quad * 4];
        int ga = tau * 16 + quad * 4;
        int rowA = row0 + (lane & 15);
        float4 o0 = make_float4(acc0[0] + bias4.x, acc0[1] + bias4.y,
                                acc0[2] + bias4.z, acc0[3] + bias4.w);
        *(float4*)&xall[rowA * 768 + ga] = o0;
        int rowB = rowA + 16;
        float4 o1 = make_float4(acc1[0] + bias4.x, acc1[1] + bias4.y,
                                acc1[2] + bias4.z, acc1[3] + bias4.w);
        *(float4*)&xall[rowB * 768 + ga] = o1;
    }
}

// ---------------------------------------------------------------------------
// Kernel C: per-segment GRU via MFMA, split-bf16 (unchanged from R5/R6).
// ---------------------------------------------------------------------------
__global__ __launch_bounds__(384) void k_gru(
    const float* __restrict__ xall,
    const unsigned short* __restrict__ wph, const unsigned short* __restrict__ wpl,
    const int* __restrict__ dur_all, const int* __restrict__ starts,
    const int* __restrict__ src_len,
    const float* __restrict__ bhf, const float* __restrict__ bhb,
    float* __restrict__ out) {
    int sblk = blockIdx.x;   // 0..6
    int b    = blockIdx.y;   // 0..7
    int dir  = blockIdx.z;   // 0 fwd, 1 bwd
    int s0 = sblk * 16;

    __shared__ __align__(16) unsigned short hbh[4 * 64 * 8];   // B-frag hi
    __shared__ __align__(16) unsigned short hbl[4 * 64 * 8];   // B-frag lo
    __shared__ __align__(16) float gbuf[16][388];              // gates [seg][g]
    __shared__ int sdur[16], sstart[16];

    int tid  = threadIdx.x;
    int wave = tid >> 6, lane = tid & 63;

    if (tid < 16) {
        int s = s0 + tid;
        sdur[tid]   = (s < SS) ? dur_all[b * SS + s] : 0;
        sstart[tid] = (s < SS) ? starts[b * SS + s]  : 0;
    }
    for (int i = tid; i < 2048; i += 384) { hbh[i] = 0; hbl[i] = 0; }

    short8 Ah[4][4], Al[4][4];
    const short8* wph8 = (const short8*)wph;
    const short8* wpl8 = (const short8*)wpl;
#pragma unroll
    for (int tt = 0; tt < 4; tt++)
#pragma unroll
        for (int k32 = 0; k32 < 4; k32++) {
            int tau = wave * 4 + tt;
            int idx = ((dir * 24 + tau) * 4 + k32) * 64 + lane;
            Ah[tt][k32] = wph8[idx];
            Al[tt][k32] = wpl8[idx];
        }

    const float* bh = dir ? bhb : bhf;
    int xbase = dir * G3;
    int seg_c = lane & 15, quad = lane >> 4;
    __syncthreads();

    int sd_[6], st_[6], sseg_[6], sj_[6];
    float h_[6], bhr_[6], bhz_[6], bhn_[6];
#pragma unroll
    for (int q = 0; q < 6; q++) {
        int u = tid + q * 384;
        if (u < 16 * DMC) {
            int seg = u >> 7, j = u & 127;
            sseg_[q] = seg; sj_[q] = j;
            sd_[q] = sdur[seg]; st_[q] = sstart[seg];
            bhr_[q] = bh[j]; bhz_[q] = bh[DMC + j]; bhn_[q] = bh[2 * DMC + j];
        } else {
            sd_[q] = 0; st_[q] = 0; sseg_[q] = 0; sj_[q] = 0;
            bhr_[q] = 0.f; bhz_[q] = 0.f; bhn_[q] = 0.f;
        }
        h_[q] = 0.f;
    }
    int slb = src_len[b];

    for (int i = 0; i < 12; i++) {
        float xr_[6], xz_[6], xn_[6];
#pragma unroll
        for (int q = 0; q < 6; q++) {
            if (i < sd_[q]) {
                int t = dir ? (st_[q] + sd_[q] - 1 - i) : (st_[q] + i);
                const float* xrow = xall + (b * TT + t) * 768 + xbase + sj_[q];
                xr_[q] = xrow[0];
                xz_[q] = xrow[DMC];
                xn_[q] = xrow[2 * DMC];
            } else { xr_[q] = 0.f; xz_[q] = 0.f; xn_[q] = 0.f; }
        }

        f32x4 acc[4];
#pragma unroll
        for (int tt = 0; tt < 4; tt++) acc[tt] = (f32x4){0.f, 0.f, 0.f, 0.f};
#pragma unroll
        for (int k32 = 0; k32 < 4; k32++) {
            short8 Bh = ((const short8*)hbh)[k32 * 64 + lane];
            short8 Bl = ((const short8*)hbl)[k32 * 64 + lane];
#pragma unroll
            for (int tt = 0; tt < 4; tt++) {
                acc[tt] = __builtin_amdgcn_mfma_f32_16x16x32_bf16(Ah[tt][k32], Bh, acc[tt], 0, 0, 0);
                acc[tt] = __builtin_amdgcn_mfma_f32_16x16x32_bf16(Ah[tt][k32], Bl, acc[tt], 0, 0, 0);
                acc[tt] = __builtin_amdgcn_mfma_f32_16x16x32_bf16(Al[tt][k32], Bh, acc[tt], 0, 0, 0);
            }
        }
#pragma unroll
        for (int tt = 0; tt < 4; tt++) {
            int g = (wave * 4 + tt) * 16 + quad * 4;    // row = quad*4+reg (m89)
            *(f32x4*)&gbuf[seg_c][g] = acc[tt];
        }
        __syncthreads();

#pragma unroll
        for (int q = 0; q < 6; q++) {
            if (i < sd_[q]) {
                int seg = sseg_[q], j = sj_[q];
                float hr = gbuf[seg][j]           + bhr_[q];
                float hz = gbuf[seg][DMC + j]     + bhz_[q];
                float hn = gbuf[seg][2 * DMC + j] + bhn_[q];
                float r = sigmoid_(xr_[q] + hr);
                float z = sigmoid_(xz_[q] + hz);
                float n = tanh_(xn_[q] + r * hn);
                float hnew = (1.f - z) * n + z * h_[q];
                h_[q] = hnew;
                unsigned short hi = f2bf(hnew);
                float hif = __uint_as_float(((unsigned)hi) << 16);
                unsigned short lo = f2bf(hnew - hif);
                int addr = ((j >> 5) * 64 + ((j & 31) >> 3) * 16 + seg) * 8 + (j & 7);
                hbh[addr] = hi;
                hbl[addr] = lo;
                if (i == sd_[q] - 1) {
                    int s = s0 + seg;
                    float vout = (s < slb) ? hnew : 0.f;
                    out[(b * SS + s) * (2 * DMC) + dir * DMC + j] = vout;
                }
            }
        }
        __syncthreads();
    }
}

// ---------------------------------------------------------------------------
extern "C" void kernel_launch(void* const* d_in, const int* in_sizes, int n_in,
                              void* d_out, int out_size, void* d_ws, size_t ws_size,
                              hipStream_t stream) {
    const float* mel      = (const float*)d_in[0];
    const int*   durations= (const int*)  d_in[1];
    const int*   mel_len  = (const int*)  d_in[2];
    const int*   src_len  = (const int*)  d_in[3];
    const float* w1       = (const float*)d_in[4];
    const float* g1       = (const float*)d_in[5];
    const float* be1      = (const float*)d_in[6];
    const float* w2       = (const float*)d_in[7];
    const float* g2       = (const float*)d_in[8];
    const float* be2      = (const float*)d_in[9];
    const float* w_ih_f   = (const float*)d_in[10];
    const float* w_hh_f   = (const float*)d_in[11];
    const float* b_ih_f   = (const float*)d_in[12];
    const float* b_hh_f   = (const float*)d_in[13];
    const float* w_ih_b   = (const float*)d_in[14];
    const float* w_hh_b   = (const float*)d_in[15];
    const float* b_ih_b   = (const float*)d_in[16];
    const float* b_hh_b   = (const float*)d_in[17];
    float* out = (float*)d_out;

    // workspace: x | xall | wph | wpl | wih_h | wih_l | biasc | starts
    float* x    = (float*)d_ws;
    float* xall = x + NROW * NM;
    unsigned short* wph   = (unsigned short*)(xall + NROW * 768);
    unsigned short* wpl   = wph + 2 * 24 * 4 * 64 * 8;
    unsigned short* wih_h = wpl + 2 * 24 * 4 * 64 * 8;
    unsigned short* wih_l = wih_h + 48 * 3 * 64 * 8;
    float* biasc = (float*)(wih_l + 48 * 3 * 64 * 8);
    int*   starts= (int*)(biasc + 768);

    k_prep<<<22, 1024, 0, stream>>>(w_hh_f, w_hh_b, w_ih_f, w_ih_b, b_ih_f, b_ih_b,
                                    durations, wph, wpl, wih_h, wih_l, biasc, starts);
    k_conv<<<dim3(TT, BB), 256, 0, stream>>>(mel, mel_len, w1, g1, be1, w2, g2, be2, x);
    k_proj<<<dim3(NROW / 32, 2), 256, 0, stream>>>(x, wih_h, wih_l, biasc, xall);
    k_gru<<<dim3(7, 8, 2), 384, 0, stream>>>(xall, wph, wpl, durations, starts, src_len,
                                             b_hh_f, b_hh_b, out);
}

// Round 8
// 181.817 us; speedup vs baseline: 1.9663x; 1.0386x over previous
//
#include <hip/hip_runtime.h>
#include <math.h>

// Problem constants
#define BB   8
#define SS   100
#define TT   1200        // S * DMAX
#define NM   80          // NMEL
#define DMC  128         // DM
#define KK   9
#define G3   384         // 3*DM
#define NROW (BB*TT)     // 9600

typedef __attribute__((ext_vector_type(8))) short short8;
typedef __attribute__((ext_vector_type(4))) float f32x4;

__device__ __forceinline__ float sigmoid_(float v) { return 1.f / (1.f + __expf(-v)); }
__device__ __forceinline__ float tanh_(float v) {
    float a = fabsf(v);
    float e = __expf(-2.f * a);
    float t = (1.f - e) / (1.f + e);
    return copysignf(t, v);
}
__device__ __forceinline__ unsigned short f2bf(float f) {   // RNE fp32->bf16
    unsigned int u = __float_as_uint(f);
    unsigned int r = (u + 0x7fffu + ((u >> 16) & 1u)) >> 16;
    return (unsigned short)r;
}

// ---------------------------------------------------------------------------
// Kernel P (fused prep), 22 blocks x 1024 thr:
//   blk 0..11  : pack w_hh into A-frag split-bf16
//   blk 12..20 : pack w_ih into A-frag split-bf16
//   blk 21     : durations prefix-scan -> starts; concat biases
// ---------------------------------------------------------------------------
__global__ __launch_bounds__(1024) void k_prep(
    const float* __restrict__ whf, const float* __restrict__ whb,
    const float* __restrict__ wif, const float* __restrict__ wib,
    const float* __restrict__ bf, const float* __restrict__ bbv,
    const int* __restrict__ dur,
    unsigned short* __restrict__ wph, unsigned short* __restrict__ wpl,
    unsigned short* __restrict__ wih_h, unsigned short* __restrict__ wih_l,
    float* __restrict__ biasc, int* __restrict__ starts) {
    int blk = blockIdx.x;
    int tid = threadIdx.x;
    if (blk < 12) {
        int idx = blk * 1024 + tid;           // [0, 12288)
        int lane = idx & 63;
        int k32  = (idx >> 6) & 3;
        int tau  = (idx >> 8) % 24;
        int dir  = idx / (24 * 4 * 64);
        const float* w = dir ? whb : whf;
        int g = tau * 16 + (lane & 15);
        int kbase = k32 * 32 + (lane >> 4) * 8;
#pragma unroll
        for (int j = 0; j < 8; j++) {
            float v = w[g * DMC + kbase + j];
            unsigned short hi = f2bf(v);
            float hif = __uint_as_float(((unsigned)hi) << 16);
            unsigned short lo = f2bf(v - hif);
            wph[idx * 8 + j] = hi;
            wpl[idx * 8 + j] = lo;
        }
    } else if (blk < 21) {
        int idx = (blk - 12) * 1024 + tid;    // [0, 9216)
        int lane = idx & 63;
        int ks   = (idx >> 6) % 3;
        int tau  = idx / (3 * 64);
        int gate = tau * 16 + (lane & 15);
        int kb   = ks * 32 + (lane >> 4) * 8;
        const float* w = (gate < G3) ? (wif + gate * NM) : (wib + (gate - G3) * NM);
#pragma unroll
        for (int j = 0; j < 8; j++) {
            int k = kb + j;
            float v = (k < NM) ? w[k] : 0.f;
            unsigned short hi = f2bf(v);
            float hif = __uint_as_float(((unsigned)hi) << 16);
            unsigned short lo = f2bf(v - hif);
            wih_h[idx * 8 + j] = hi;
            wih_l[idx * 8 + j] = lo;
        }
    } else {
        __shared__ int buf[BB][128];
        int s = tid & 127, b = tid >> 7;
        int v = (s < SS) ? dur[b * SS + s] : 0;
        buf[b][s] = v;
        __syncthreads();
        for (int off = 1; off < 128; off <<= 1) {
            int t = (s >= off) ? buf[b][s - off] : 0;
            __syncthreads();
            buf[b][s] += t;
            __syncthreads();
        }
        if (s < SS) starts[b * SS + s] = buf[b][s] - v;
        if (tid < 768) biasc[tid] = (tid < G3) ? bf[tid] : bbv[tid - G3];
    }
}

// ---------------------------------------------------------------------------
// Kernel A: fused conv1+BN/ReLU+conv2+BN/ReLU — register-resident, SPILL-FREE
// (unchanged from R7: VGPR 52, no scratch, VALU-bound at 78%).
// ---------------------------------------------------------------------------
__global__ __launch_bounds__(256) void k_conv(
    const float* __restrict__ mel, const int* __restrict__ mel_len,
    const float* __restrict__ w1, const float* __restrict__ g1, const float* __restrict__ be1,
    const float* __restrict__ w2, const float* __restrict__ g2, const float* __restrict__ be2,
    float* __restrict__ xout) {
    int b = blockIdx.y;
    int t = blockIdx.x;
    int ml = mel_len[b];
    if (t >= ml) return;

    __shared__ __align__(16) float mp[96];          // mp[i] = mel[i-8], i in [8,88)
    __shared__ __align__(16) float part[8][84];     // octet partials

    int tid = threadIdx.x;
    int mq = tid >> 6, g = tid & 63;
    int ms = 20 * mq;
    const float inv_sqrt = 0.9999950000374997f;     // 1/sqrt(1+1e-5)

    if (tid < 96) {
        float v = 0.f;
        if (tid >= 8 && tid < 88) v = mel[(b * TT + t) * NM + tid - 8];
        mp[tid] = v;
    }
    __syncthreads();

    float c[20];
#pragma unroll
    for (int m = 0; m < 20; m++) c[m] = 0.f;

#pragma unroll 1
    for (int dd = 0; dd < 2; dd++) {
        int d = g + 64 * dd;
        float sc = g1[d] * inv_sqrt;
        float w1r[KK], w2r[KK];
#pragma unroll
        for (int k = 0; k < KK; k++) { w1r[k] = w1[d * KK + k] * sc; w2r[k] = w2[d * KK + k]; }
        float sb = be1[d];

        float mw[12];
        {
            const float4* p4 = (const float4*)(mp + ms);
            float4 a = p4[0], bq = p4[1], cq = p4[2];
            mw[0]=a.x;  mw[1]=a.y;  mw[2]=a.z;  mw[3]=a.w;
            mw[4]=bq.x; mw[5]=bq.y; mw[6]=bq.z; mw[7]=bq.w;
            mw[8]=cq.x; mw[9]=cq.y; mw[10]=cq.z; mw[11]=cq.w;
        }
#pragma unroll
        for (int ch = 0; ch < 7; ch++) {
#pragma unroll
            for (int jj = 0; jj < 4; jj++) {
                int off = ch * 4 + jj;
                float yv = sb;
#pragma unroll
                for (int k = 0; k < KK; k++) yv = fmaf(w1r[k], mw[jj + k], yv);
                yv = fmaxf(yv, 0.f);
                int j = ms + off;
                if (j < 4 || j >= 84) yv = 0.f;
#pragma unroll
                for (int k = 0; k < KK; k++) {
                    int mo = off - k;
                    if (mo >= 0 && mo < 20) c[mo] = fmaf(w2r[k], yv, c[mo]);
                }
            }
            if (ch < 6) {
#pragma unroll
                for (int q = 0; q < 8; q++) mw[q] = mw[q + 4];
                const float4* p4 = (const float4*)(mp + ms + ch * 4 + 12);
                float4 a = p4[0];
                mw[8]=a.x; mw[9]=a.y; mw[10]=a.z; mw[11]=a.w;
            }
        }
    }

#pragma unroll
    for (int m = 0; m < 20; m++) {
        c[m] += __shfl_xor(c[m], 1);
        c[m] += __shfl_xor(c[m], 2);
        c[m] += __shfl_xor(c[m], 4);
    }
    if ((g & 7) == 0) {
        int p = g >> 3;
#pragma unroll
        for (int m = 0; m < 20; m += 4)
            *(float4*)&part[p][ms + m] = make_float4(c[m], c[m+1], c[m+2], c[m+3]);
    }
    __syncthreads();

    if (tid < 80) {
        float s = 0.f;
#pragma unroll
        for (int p = 0; p < 8; p++) s += part[p][tid];
        float v = fmaxf(0.f, fmaf(s, g2[0] * inv_sqrt, be2[0]));
        xout[(b * TT + t) * NM + tid] = v;
    }
}

// ---------------------------------------------------------------------------
// Kernel B: projection GEMM via split-bf16 MFMA (unchanged).
// ---------------------------------------------------------------------------
__global__ __launch_bounds__(256) void k_proj(
    const float* __restrict__ x,
    const unsigned short* __restrict__ wih_h, const unsigned short* __restrict__ wih_l,
    const float* __restrict__ biasc,
    float* __restrict__ xall) {
    __shared__ short8 bhs[2 * 3 * 64];
    __shared__ short8 bls[2 * 3 * 64];

    int tid = threadIdx.x;
    int wave = tid >> 6, lane = tid & 63, quad = lane >> 4;
    int row0 = blockIdx.x * 32;
    int tau0 = blockIdx.y * 24;

    for (int i = tid; i < 2 * 3 * 64; i += 256) {
        int rg = i / 192, rem = i - rg * 192;
        int ks = rem >> 6, ln = rem & 63;
        int row = row0 + rg * 16 + (ln & 15);
        int kb = ks * 32 + (ln >> 4) * 8;
        short8 hi8, lo8;
#pragma unroll
        for (int j = 0; j < 8; j++) {
            int k = kb + j;
            float v = (k < NM) ? x[row * NM + k] : 0.f;
            unsigned short hi = f2bf(v);
            float hif = __uint_as_float(((unsigned)hi) << 16);
            hi8[j] = (short)hi;
            lo8[j] = (short)f2bf(v - hif);
        }
        bhs[i] = hi8;
        bls[i] = lo8;
    }
    __syncthreads();

    const short8* wih_h8 = (const short8*)wih_h;
    const short8* wih_l8 = (const short8*)wih_l;

    for (int tt = 0; tt < 6; tt++) {
        int tau = tau0 + wave * 6 + tt;
        short8 Ah[3], Al[3];
#pragma unroll
        for (int ks = 0; ks < 3; ks++) {
            int ia = (tau * 3 + ks) * 64 + lane;
            Ah[ks] = wih_h8[ia];
            Al[ks] = wih_l8[ia];
        }
        f32x4 acc0 = (f32x4){0.f,0.f,0.f,0.f}, acc1 = (f32x4){0.f,0.f,0.f,0.f};
#pragma unroll
        for (int ks = 0; ks < 3; ks++) {
            short8 Bh0 = bhs[ks * 64 + lane],       Bl0 = bls[ks * 64 + lane];
            short8 Bh1 = bhs[192 + ks * 64 + lane], Bl1 = bls[192 + ks * 64 + lane];
            acc0 = __builtin_amdgcn_mfma_f32_16x16x32_bf16(Ah[ks], Bh0, acc0, 0, 0, 0);
            acc0 = __builtin_amdgcn_mfma_f32_16x16x32_bf16(Ah[ks], Bl0, acc0, 0, 0, 0);
            acc0 = __builtin_amdgcn_mfma_f32_16x16x32_bf16(Al[ks], Bh0, acc0, 0, 0, 0);
            acc1 = __builtin_amdgcn_mfma_f32_16x16x32_bf16(Ah[ks], Bh1, acc1, 0, 0, 0);
            acc1 = __builtin_amdgcn_mfma_f32_16x16x32_bf16(Ah[ks], Bl1, acc1, 0, 0, 0);
            acc1 = __builtin_amdgcn_mfma_f32_16x16x32_bf16(Al[ks], Bh1, acc1, 0, 0, 0);
        }
        float4 bias4 = *(const float4*)&biasc[tau * 16 + quad * 4];
        int ga = tau * 16 + quad * 4;
        int rowA = row0 + (lane & 15);
        float4 o0 = make_float4(acc0[0] + bias4.x, acc0[1] + bias4.y,
                                acc0[2] + bias4.z, acc0[3] + bias4.w);
        *(float4*)&xall[rowA * 768 + ga] = o0;
        int rowB = rowA + 16;
        float4 o1 = make_float4(acc1[0] + bias4.x, acc1[1] + bias4.y,
                                acc1[2] + bias4.z, acc1[3] + bias4.w);
        *(float4*)&xall[rowB * 768 + ga] = o1;
    }
}

// ---------------------------------------------------------------------------
// Kernel C (R8 rewrite): per-segment GRU, LANE-LOCAL gate update.
// 512 thr = 8 waves. Wave w owns tau tiles {w, w+8, w+16} -> C-layout puts
// gates (j, 128+j, 256+j) for j = w*16+quad*4..+3, seg = lane&15 in ONE
// lane's 3 accumulators. h is a per-lane float4 in registers; split-bf16
// B-frag copy of h is ping-ponged in LDS -> ONE barrier per iteration, no
// gbuf, no hs. x-gates loaded as 3 float4 (was 18 scalars).
// ---------------------------------------------------------------------------
__global__ __launch_bounds__(512) void k_gru(
    const float* __restrict__ xall,
    const unsigned short* __restrict__ wph, const unsigned short* __restrict__ wpl,
    const int* __restrict__ dur_all, const int* __restrict__ starts,
    const int* __restrict__ src_len,
    const float* __restrict__ bhf, const float* __restrict__ bhb,
    float* __restrict__ out) {
    int sblk = blockIdx.x;   // 0..6
    int b    = blockIdx.y;   // 0..7
    int dir  = blockIdx.z;   // 0 fwd, 1 bwd
    int s0 = sblk * 16;

    __shared__ __align__(16) unsigned short hbh[2][2048];   // ping-pong B-frag hi
    __shared__ __align__(16) unsigned short hbl[2][2048];   // ping-pong B-frag lo

    int tid  = threadIdx.x;
    int wave = tid >> 6, lane = tid & 63;
    int quad = lane >> 4, seg = lane & 15;

    for (int i = tid; i < 2048; i += 512) {
        hbh[0][i] = 0; hbl[0][i] = 0; hbh[1][i] = 0; hbl[1][i] = 0;
    }

    // ---- A-fragments: taus {wave, wave+8, wave+16}, persist in VGPRs ----
    short8 Ah[3][4], Al[3][4];
    const short8* wph8 = (const short8*)wph;
    const short8* wpl8 = (const short8*)wpl;
#pragma unroll
    for (int tt = 0; tt < 3; tt++)
#pragma unroll
        for (int k32 = 0; k32 < 4; k32++) {
            int tau = wave + 8 * tt;
            int idx = ((dir * 24 + tau) * 4 + k32) * 64 + lane;
            Ah[tt][k32] = wph8[idx];
            Al[tt][k32] = wpl8[idx];
        }

    // ---- per-lane segment metadata (seg fixed for this lane) ----
    int s = s0 + seg;
    int sd = (s < SS) ? dur_all[b * SS + s] : 0;
    int st = (s < SS) ? starts[b * SS + s]  : 0;
    int slb = src_len[b];
    const float* bh = dir ? bhb : bhf;
    int j0 = wave * 16 + quad * 4;               // this lane's 4 hidden dims
    float4 bhr = *(const float4*)&bh[j0];
    float4 bhz = *(const float4*)&bh[DMC + j0];
    float4 bhn = *(const float4*)&bh[2 * DMC + j0];
    float4 h = make_float4(0.f, 0.f, 0.f, 0.f);

    // LDS B-frag address for k = j0..j0+3 (8B-contiguous)
    int idx8 = (j0 >> 5) * 64 + ((j0 >> 3) & 3) * 16 + seg;
    int wbase = idx8 * 8 + (j0 & 7);             // in shorts

    __syncthreads();

    for (int i = 0; i < 12; i++) {
        int p = i & 1;
        bool act = (i < sd);

        // ---- prefetch x-gates (independent of LDS state) ----
        float4 xr = make_float4(0.f,0.f,0.f,0.f), xz = xr, xn = xr;
        if (act) {
            int t = dir ? (st + sd - 1 - i) : (st + i);
            const float* xrow = xall + (size_t)(b * TT + t) * 768 + dir * G3 + j0;
            xr = *(const float4*)&xrow[0];
            xz = *(const float4*)&xrow[DMC];
            xn = *(const float4*)&xrow[2 * DMC];
        }

        // ---- MFMA: acc[0]=r-gates, acc[1]=z, acc[2]=n (3-term split-bf16) ----
        f32x4 acc[3];
#pragma unroll
        for (int tt = 0; tt < 3; tt++) acc[tt] = (f32x4){0.f, 0.f, 0.f, 0.f};
#pragma unroll
        for (int k32 = 0; k32 < 4; k32++) {
            short8 Bh = ((const short8*)hbh[p])[k32 * 64 + lane];
            short8 Bl = ((const short8*)hbl[p])[k32 * 64 + lane];
#pragma unroll
            for (int tt = 0; tt < 3; tt++) {
                acc[tt] = __builtin_amdgcn_mfma_f32_16x16x32_bf16(Ah[tt][k32], Bh, acc[tt], 0, 0, 0);
                acc[tt] = __builtin_amdgcn_mfma_f32_16x16x32_bf16(Ah[tt][k32], Bl, acc[tt], 0, 0, 0);
                acc[tt] = __builtin_amdgcn_mfma_f32_16x16x32_bf16(Al[tt][k32], Bh, acc[tt], 0, 0, 0);
            }
        }

        // ---- lane-local GRU update (C row = quad*4+reg == j0+reg, col = seg) ----
        if (act) {
            float hv[4] = {h.x, h.y, h.z, h.w};
            float xrv[4] = {xr.x, xr.y, xr.z, xr.w};
            float xzv[4] = {xz.x, xz.y, xz.z, xz.w};
            float xnv[4] = {xn.x, xn.y, xn.z, xn.w};
            float bhrv[4] = {bhr.x, bhr.y, bhr.z, bhr.w};
            float bhzv[4] = {bhz.x, bhz.y, bhz.z, bhz.w};
            float bhnv[4] = {bhn.x, bhn.y, bhn.z, bhn.w};
#pragma unroll
            for (int cmp = 0; cmp < 4; cmp++) {
                float r = sigmoid_(xrv[cmp] + acc[0][cmp] + bhrv[cmp]);
                float z = sigmoid_(xzv[cmp] + acc[1][cmp] + bhzv[cmp]);
                float n = tanh_(xnv[cmp] + r * (acc[2][cmp] + bhnv[cmp]));
                hv[cmp] = (1.f - z) * n + z * hv[cmp];
            }
            h = make_float4(hv[0], hv[1], hv[2], hv[3]);
            if (i == sd - 1) {
                float4 vout = (s < slb) ? h : make_float4(0.f, 0.f, 0.f, 0.f);
                *(float4*)&out[(b * SS + s) * (2 * DMC) + dir * DMC + j0] = vout;
            }
        }

        // ---- write h (updated or carried) to the OTHER buffer, split-bf16 ----
        {
            float hv[4] = {h.x, h.y, h.z, h.w};
            ushort4 hi4, lo4;
            unsigned short hs_[4], ls_[4];
#pragma unroll
            for (int cmp = 0; cmp < 4; cmp++) {
                unsigned short hi = f2bf(hv[cmp]);
                float hif = __uint_as_float(((unsigned)hi) << 16);
                hs_[cmp] = hi;
                ls_[cmp] = f2bf(hv[cmp] - hif);
            }
            hi4 = make_ushort4(hs_[0], hs_[1], hs_[2], hs_[3]);
            lo4 = make_ushort4(ls_[0], ls_[1], ls_[2], ls_[3]);
            *(ushort4*)&hbh[1 - p][wbase] = hi4;
            *(ushort4*)&hbl[1 - p][wbase] = lo4;
        }
        __syncthreads();
    }
}

// ---------------------------------------------------------------------------
extern "C" void kernel_launch(void* const* d_in, const int* in_sizes, int n_in,
                              void* d_out, int out_size, void* d_ws, size_t ws_size,
                              hipStream_t stream) {
    const float* mel      = (const float*)d_in[0];
    const int*   durations= (const int*)  d_in[1];
    const int*   mel_len  = (const int*)  d_in[2];
    const int*   src_len  = (const int*)  d_in[3];
    const float* w1       = (const float*)d_in[4];
    const float* g1       = (const float*)d_in[5];
    const float* be1      = (const float*)d_in[6];
    const float* w2       = (const float*)d_in[7];
    const float* g2       = (const float*)d_in[8];
    const float* be2      = (const float*)d_in[9];
    const float* w_ih_f   = (const float*)d_in[10];
    const float* w_hh_f   = (const float*)d_in[11];
    const float* b_ih_f   = (const float*)d_in[12];
    const float* b_hh_f   = (const float*)d_in[13];
    const float* w_ih_b   = (const float*)d_in[14];
    const float* w_hh_b   = (const float*)d_in[15];
    const float* b_ih_b   = (const float*)d_in[16];
    const float* b_hh_b   = (const float*)d_in[17];
    float* out = (float*)d_out;

    // workspace: x | xall | wph | wpl | wih_h | wih_l | biasc | starts
    float* x    = (float*)d_ws;
    float* xall = x + NROW * NM;
    unsigned short* wph   = (unsigned short*)(xall + NROW * 768);
    unsigned short* wpl   = wph + 2 * 24 * 4 * 64 * 8;
    unsigned short* wih_h = wpl + 2 * 24 * 4 * 64 * 8;
    unsigned short* wih_l = wih_h + 48 * 3 * 64 * 8;
    float* biasc = (float*)(wih_l + 48 * 3 * 64 * 8);
    int*   starts= (int*)(biasc + 768);

    k_prep<<<22, 1024, 0, stream>>>(w_hh_f, w_hh_b, w_ih_f, w_ih_b, b_ih_f, b_ih_b,
                                    durations, wph, wpl, wih_h, wih_l, biasc, starts);
    k_conv<<<dim3(TT, BB), 256, 0, stream>>>(mel, mel_len, w1, g1, be1, w2, g2, be2, x);
    k_proj<<<dim3(NROW / 32, 2), 256, 0, stream>>>(x, wih_h, wih_l, biasc, xall);
    k_gru<<<dim3(7, 8, 2), 512, 0, stream>>>(xall, wph, wpl, durations, starts, src_len,
                                             b_hh_f, b_hh_b, out);
}